// Round 4
// baseline (1392.690 us; speedup 1.0000x reference)
//
#include <hip/hip_runtime.h>
#include <hip/hip_bf16.h>
#include <math.h>

#define BB 16
#define LL 4095
#define DD 768
#define TT 768
#define SS 64
#define KK 8
#define HH 384
#define G3 1152   // 3*H
#define NWPD 24   // WGs per direction for the coop scan

// ---------- 1. span means ----------
__global__ void span_mean_kernel(const float* __restrict__ hidden,
                                 const int* __restrict__ sstart,
                                 const int* __restrict__ slen,
                                 float* __restrict__ span) {
    int bs = blockIdx.x;            // b*64+s
    int b = bs >> 6;
    int st = sstart[bs];
    int ln = slen[bs];
    const float* base = hidden + ((size_t)b * LL + st) * DD;
    float inv = 1.0f / (float)ln;
    for (int d = threadIdx.x; d < DD; d += 256) {
        float acc = 0.0f;
        for (int r = 0; r < ln; ++r) acc += base[(size_t)r * DD + d];
        span[(size_t)bs * DD + d] = acc * inv;
    }
}

// ---------- 2. ctx accumulation (atomic partial sums) ----------
__global__ void ctx_accum_kernel(const float* __restrict__ hidden,
                                 const int* __restrict__ attn_len,
                                 float* __restrict__ ctx) {
    int b = blockIdx.x, chunk = blockIdx.y;
    int lim = attn_len[b] - 1;
    int l0 = chunk * 128;
    int l1 = min(l0 + 128, lim);
    if (l0 >= l1) return;
    int t = threadIdx.x;
    const float* base = hidden + (size_t)b * LL * DD;
    float a0 = 0.f, a1 = 0.f, a2 = 0.f;
    for (int l = l0; l < l1; ++l) {
        const float* row = base + (size_t)l * DD;
        a0 += row[t]; a1 += row[t + 256]; a2 += row[t + 512];
    }
    atomicAdd(&ctx[b * DD + t], a0);
    atomicAdd(&ctx[b * DD + t + 256], a1);
    atomicAdd(&ctx[b * DD + t + 512], a2);
}

// ---------- 3. rep_context = (ctx/n) @ W_ctx^T + b_ctx ----------
__global__ void repctx_kernel(const float* __restrict__ ctxsum,
                              const int* __restrict__ attn_len,
                              const float* __restrict__ W_ctx,
                              const float* __restrict__ b_ctx,
                              float* __restrict__ out_rc) {
    int b = blockIdx.x;
    int j = blockIdx.y * 256 + threadIdx.x;
    __shared__ float cv[DD];
    float inv = 1.0f / (float)(attn_len[b] - 1);
    for (int d = threadIdx.x; d < DD; d += 256) cv[d] = ctxsum[b * DD + d] * inv;
    __syncthreads();
    const float* wr = W_ctx + (size_t)j * DD;
    float acc = b_ctx[j];
    for (int d = 0; d < DD; ++d) acc += wr[d] * cv[d];
    out_rc[b * TT + j] = acc;
}

// ---------- 4. gi = span @ W_ih^T + b_ih (+ b_hh for r,z gates) ----------
// LDS tiles stored TRANSPOSED [k][m] so the inner loop is 2x ds_read_b128
// + 16 FMA per kk (FMA-bound) instead of 8x ds_read_b32 (LDS-pipe-bound).
__global__ __launch_bounds__(256) void gi_gemm_kernel(
        const float* __restrict__ span,
        const float* __restrict__ Wf, const float* __restrict__ Wb,
        const float* __restrict__ bihf, const float* __restrict__ bhhf,
        const float* __restrict__ bihb, const float* __restrict__ bhhb,
        float* __restrict__ gi) {
    int dir = blockIdx.z;
    const float* W = dir ? Wb : Wf;
    const float* bih = dir ? bihb : bihf;
    const float* bhh = dir ? bhhb : bhhf;
    int m0 = blockIdx.x * 64, n0 = blockIdx.y * 64;
    __shared__ float As[16][68];   // [k][m], pad 68 (2-way max on stage writes)
    __shared__ float Bs[16][68];
    int t = threadIdx.x, tx = t & 15, ty = t >> 4;
    float acc[4][4] = {{0.f}};
    for (int k0 = 0; k0 < DD; k0 += 16) {
        for (int e = t; e < 1024; e += 256) {
            int r = e >> 4, c = e & 15;
            As[c][r] = span[(size_t)(m0 + r) * DD + k0 + c];
            Bs[c][r] = W[(size_t)(n0 + r) * DD + k0 + c];
        }
        __syncthreads();
#pragma unroll
        for (int kk = 0; kk < 16; ++kk) {
            float4 a4 = *(const float4*)&As[kk][ty * 4];
            float4 b4 = *(const float4*)&Bs[kk][tx * 4];
            float a[4] = {a4.x, a4.y, a4.z, a4.w};
            float bv[4] = {b4.x, b4.y, b4.z, b4.w};
#pragma unroll
            for (int i = 0; i < 4; ++i)
#pragma unroll
                for (int j = 0; j < 4; ++j) acc[i][j] += a[i] * bv[j];
        }
        __syncthreads();
    }
#pragma unroll
    for (int i = 0; i < 4; ++i)
#pragma unroll
        for (int j = 0; j < 4; ++j) {
            int m = m0 + ty * 4 + i, n = n0 + tx * 4 + j;
            float v = acc[i][j] + bih[n] + (n < 2 * HH ? bhh[n] : 0.0f);
            gi[((size_t)dir * 1024 + m) * G3 + n] = v;
        }
}

// ---------- 5. GRU coop scan: W stationary in VGPRs, 24 WGs/dir ----------
// Tagged-pair protocol (R3) + two critical-path cuts:
//  (a) LDS h double-buffer -> NO end-of-step barrier -> the agent-scope
//      publish store is fire-and-forget (no s_waitcnt vmcnt(0) drain of a
//      MALL-bound store on the critical path). One barrier per step.
//  (b) own-value LDS bypass: each thread writes its hnew directly into the
//      next step's LDS buffer; the poll checks/stages only the 23 FOREIGN
//      WGs' pairs (ownmask skip). Removes the WG's own store->load MALL
//      round-trip from every step's detect (own values are always the
//      freshest, so they were the likely max of the detect each step).
// Payloads are staged to LDS inside the poll round (value consumed
// immediately -> no 24-reg live range; stale rounds are overwritten by the
// successful round).
__global__ __launch_bounds__(256, 1) void scan_coop_kernel(
        const float* __restrict__ gi,
        const float* __restrict__ Whf, const float* __restrict__ Whb,
        const float* __restrict__ bhhf, const float* __restrict__ bhhb,
        unsigned long long* __restrict__ hpair,  // [2 parity][2 dir][16 b][384]
        float* __restrict__ repac) {
    int wg = blockIdx.x;            // 0..47
    int dir = wg / NWPD;
    int w = wg % NWPD;
    int t = threadIdx.x;
    int kseg = t & 15, i_loc = t >> 4;
    int i_glob = w * 16 + i_loc;
    const float* Wh = dir ? Whb : Whf;

    // W fragments into registers (once):
    // thread (i_loc,kseg) holds W[g][i_glob][k] for k in {kseg*4 + 64j + q}
    float4 wr[3][6];
#pragma unroll
    for (int g = 0; g < 3; ++g)
#pragma unroll
        for (int j = 0; j < 6; ++j) {
            wr[g][j] = *(const float4*)(Wh + (size_t)(g * HH + i_glob) * HH + kseg * 4 + 64 * j);
            // opaque per-scalar touch: keeps the tile resident in VGPRs
            asm volatile("" : "+v"(wr[g][j].x), "+v"(wr[g][j].y),
                              "+v"(wr[g][j].z), "+v"(wr[g][j].w));
        }
    float bhn = (dir ? bhhb : bhhf)[2 * HH + i_glob];

    __shared__ __align__(16) float hsbuf[2][6144];    // double-buffered [16 b][384]

    // ownmask: bit j set iff pair (j*256+t) is produced by THIS WG.
    // pair q = b*384 + i ; producer WG = i>>4 = (q%384)>>4.
    unsigned ownmask = 0u;
#pragma unroll
    for (int j = 0; j < 24; ++j)
        if ((((j * 256 + t) % 384) >> 4) == w) ownmask |= (1u << j);

    // h0 = 0: init own slots of buffer 0 (foreign slots staged from the
    // zeroed hpair at s=0)
    hsbuf[0][kseg * 384 + i_glob] = 0.0f;

    for (int s = 0; s < 64; ++s) {
        float* hs  = hsbuf[s & 1];
        float* hsN = hsbuf[(s + 1) & 1];
        const float4* hs4 = (const float4*)hs;
        int p = dir ? (63 - s) : s;
        // ---- gi loads for this thread's output; issued before the poll ----
        const float* grow = gi + ((size_t)dir * 1024 + kseg * 64 + p) * G3;
        float g_r = grow[i_glob], g_z = grow[HH + i_glob], g_n = grow[2 * HH + i_glob];
        // ---- poll foreign tagged pairs; stage payload in-place ----
        {
            const unsigned long long* src = hpair + (size_t)((s & 1) * 2 + dir) * 6144;
            unsigned int expect = (unsigned int)s;
            for (;;) {
                bool ok = true;
#pragma unroll
                for (int j = 0; j < 24; ++j) {
                    if ((ownmask >> j) & 1u) continue;
                    unsigned long long v = __hip_atomic_load(src + j * 256 + t,
                                                __ATOMIC_RELAXED, __HIP_MEMORY_SCOPE_AGENT);
                    hs[j * 256 + t] = __uint_as_float((unsigned int)v);
                    ok &= ((unsigned int)(v >> 32) == expect);
                }
                if (ok) break;
                __builtin_amdgcn_s_sleep(1);
            }
        }
        __syncthreads();   // the ONLY barrier per step
        // ---- partials for all 16 batches over this thread's k-set ----
        float pr[16], pz[16], pn[16];
#pragma unroll
        for (int b = 0; b < 16; ++b) {
            float4 hq[6];
#pragma unroll
            for (int j = 0; j < 6; ++j) hq[j] = hs4[b * 96 + kseg + 16 * j];
            float ar = 0.f, az = 0.f, an = 0.f;
#pragma unroll
            for (int j = 0; j < 6; ++j) {
                ar += wr[0][j].x * hq[j].x + wr[0][j].y * hq[j].y + wr[0][j].z * hq[j].z + wr[0][j].w * hq[j].w;
                az += wr[1][j].x * hq[j].x + wr[1][j].y * hq[j].y + wr[1][j].z * hq[j].z + wr[1][j].w * hq[j].w;
                an += wr[2][j].x * hq[j].x + wr[2][j].y * hq[j].y + wr[2][j].z * hq[j].z + wr[2][j].w * hq[j].w;
            }
            pr[b] = ar; pz[b] = az; pn[b] = an;
        }
        // ---- butterfly reduce across the 16 kseg lanes; end: b == kseg ----
        float qr[8], qz[8], qn[8];
        {
            const bool hi = (kseg & 8) != 0;
#pragma unroll
            for (int j = 0; j < 8; ++j) {
                float sr_ = hi ? pr[j] : pr[j + 8];
                qr[j] = (hi ? pr[j + 8] : pr[j]) + __shfl_xor(sr_, 8);
                float sz_ = hi ? pz[j] : pz[j + 8];
                qz[j] = (hi ? pz[j + 8] : pz[j]) + __shfl_xor(sz_, 8);
                float sn_ = hi ? pn[j] : pn[j + 8];
                qn[j] = (hi ? pn[j + 8] : pn[j]) + __shfl_xor(sn_, 8);
            }
        }
        float ur[4], uz[4], un[4];
        {
            const bool hi = (kseg & 4) != 0;
#pragma unroll
            for (int j = 0; j < 4; ++j) {
                float sr_ = hi ? qr[j] : qr[j + 4];
                ur[j] = (hi ? qr[j + 4] : qr[j]) + __shfl_xor(sr_, 4);
                float sz_ = hi ? qz[j] : qz[j + 4];
                uz[j] = (hi ? qz[j + 4] : qz[j]) + __shfl_xor(sz_, 4);
                float sn_ = hi ? qn[j] : qn[j + 4];
                un[j] = (hi ? qn[j + 4] : qn[j]) + __shfl_xor(sn_, 4);
            }
        }
        float vr[2], vz[2], vn[2];
        {
            const bool hi = (kseg & 2) != 0;
#pragma unroll
            for (int j = 0; j < 2; ++j) {
                float sr_ = hi ? ur[j] : ur[j + 2];
                vr[j] = (hi ? ur[j + 2] : ur[j]) + __shfl_xor(sr_, 2);
                float sz_ = hi ? uz[j] : uz[j + 2];
                vz[j] = (hi ? uz[j + 2] : uz[j]) + __shfl_xor(sz_, 2);
                float sn_ = hi ? un[j] : un[j + 2];
                vn[j] = (hi ? un[j + 2] : un[j]) + __shfl_xor(sn_, 2);
            }
        }
        float sr, sz, sn;
        {
            const bool hi = (kseg & 1) != 0;
            float sr_ = hi ? vr[0] : vr[1];
            sr = (hi ? vr[1] : vr[0]) + __shfl_xor(sr_, 1);
            float sz_ = hi ? vz[0] : vz[1];
            sz = (hi ? vz[1] : vz[0]) + __shfl_xor(sz_, 1);
            float sn_ = hi ? vn[0] : vn[1];
            sn = (hi ? vn[1] : vn[0]) + __shfl_xor(sn_, 1);
        }
        // ---- epilogue: every thread owns one (b = kseg, i_glob) output ----
        float r = 1.0f / (1.0f + expf(-(g_r + sr)));
        float z = 1.0f / (1.0f + expf(-(g_z + sz)));
        float n = tanhf(g_n + r * (sn + bhn));
        float hold = hs[kseg * 384 + i_glob];
        float hnew = (1.0f - z) * n + z * hold;
        // own-value LDS bypass for next step
        hsN[kseg * 384 + i_glob] = hnew;
        // publish {tag = s+1, h} for FOREIGN WGs (fire-and-forget)
        unsigned long long pv = ((unsigned long long)(unsigned int)(s + 1) << 32)
                              | (unsigned long long)__float_as_uint(hnew);
        __hip_atomic_store(hpair + (size_t)(((s + 1) & 1) * 2 + dir) * 6144 + kseg * 384 + i_glob,
                           pv, __ATOMIC_RELAXED, __HIP_MEMORY_SCOPE_AGENT);
        repac[(size_t)(kseg * 64 + p) * TT + dir * HH + i_glob] = hnew;
        // no end barrier: hs double-buffer makes it unnecessary
    }
}

// ---------- 6. q and k dot products (one wave each, fp64 accumulation) ----------
__global__ void qkv_kernel(const float* __restrict__ repac,
                           const float* __restrict__ repctx,
                           const float* __restrict__ Wfind,
                           float* __restrict__ qv, float* __restrict__ kv) {
    int w = blockIdx.x * 4 + (threadIdx.x >> 6);
    int lane = threadIdx.x & 63;
    const float* row;
    const float* vec;
    float* dst;
    if (w < 1024) {
        row = repac + (size_t)w * TT;
        vec = Wfind;
        dst = qv + w;
    } else {
        int u = w - 1024;
        int b = u / 65, j = u % 65;
        row = (j < 64) ? (repac + (size_t)(b * 64 + j) * TT) : (repctx + (size_t)b * TT);
        vec = Wfind + TT;
        dst = kv + u;
    }
    double acc = 0.0;
    for (int d = lane; d < TT; d += 64) acc += (double)row[d] * (double)vec[d];
#pragma unroll
    for (int off = 32; off > 0; off >>= 1) acc += __shfl_down(acc, off);
    if (lane == 0) *dst = (float)acc;
}

// ---------- 7. top-k on fp32-quantized scores (np-mirrored), tie -> lower idx ----------
__global__ void topk_kernel(const float* __restrict__ qv,
                            const float* __restrict__ kv,
                            float* __restrict__ vals_out,
                            float* __restrict__ idx_out,
                            int* __restrict__ idxw) {
    int t = threadIdx.x;
    int bs = blockIdx.x * 256 + t;
    int b = bs >> 6;
    int b0 = (blockIdx.x * 256) >> 6;       // 4 batches per block
    __shared__ float kvs[4 * 65];
    for (int e = t; e < 4 * 65; e += 256) kvs[e] = kv[(b0 + e / 65) * 65 + e % 65];
    __syncthreads();
    const float* myk = kvs + (b - b0) * 65;
    float q = qv[bs];
    float sc[65];
#pragma unroll 1
    for (int j = 0; j < 65; ++j) {
        float x = q + myk[j];                 // fp32 add, as np broadcast-add
        float e = (float)exp(-(double)x);     // ~correctly-rounded f32 exp
        sc[j] = 1.0f / (1.0f + e);            // fp32 add + fp32 divide, as np
    }
    unsigned long long taken = 0ull;
    bool tk64 = false;
    for (int kk = 0; kk < 8; ++kk) {
        float best = -3.0e38f;
        int bj = 0;
        for (int j = 0; j < 65; ++j) {
            bool tkn = (j < 64) ? (((taken >> j) & 1ull) != 0ull) : tk64;
            float v = sc[j];
            if (!tkn && v > best) { best = v; bj = j; }   // strict > => lowest index wins ties
        }
        if (bj < 64) taken |= (1ull << bj); else tk64 = true;
        vals_out[bs * 8 + kk] = best;
        idx_out[bs * 8 + kk] = (float)bj;
        idxw[bs * 8 + kk] = bj;
    }
}

// ---------- 8. v1 gather ----------
__global__ void v1_kernel(const float* __restrict__ repac,
                          const float* __restrict__ repctx,
                          const int* __restrict__ idxw,
                          float* __restrict__ v1) {
    int bs = blockIdx.x;
    int b = bs >> 6;
    int t = threadIdx.x;
    for (int kk = 0; kk < 8; ++kk) {
        int j = idxw[bs * 8 + kk];
        const float* src = (j < 64) ? (repac + (size_t)(b * 64 + j) * TT)
                                    : (repctx + (size_t)b * TT);
        float* dst = v1 + ((size_t)bs * 8 + kk) * TT;
        for (int d = t; d < DD; d += 256) dst[d] = src[d];
    }
}

extern "C" void kernel_launch(void* const* d_in, const int* in_sizes, int n_in,
                              void* d_out, int out_size, void* d_ws, size_t ws_size,
                              hipStream_t stream) {
    const float* hidden    = (const float*)d_in[0];
    const float* W_ih_f    = (const float*)d_in[1];
    const float* W_hh_f    = (const float*)d_in[2];
    const float* b_ih_f    = (const float*)d_in[3];
    const float* b_hh_f    = (const float*)d_in[4];
    const float* W_ih_b    = (const float*)d_in[5];
    const float* W_hh_b    = (const float*)d_in[6];
    const float* b_ih_b    = (const float*)d_in[7];
    const float* b_hh_b    = (const float*)d_in[8];
    const float* W_ctx     = (const float*)d_in[9];
    const float* b_ctx     = (const float*)d_in[10];
    const float* W_find    = (const float*)d_in[11];
    const int*   attn_len  = (const int*)d_in[12];
    const int*   span_start= (const int*)d_in[13];
    const int*   span_len  = (const int*)d_in[14];
    (void)in_sizes; (void)n_in; (void)out_size; (void)ws_size;

    // workspace layout (floats)
    float* ws   = (float*)d_ws;
    float* span = ws;                       // 786432
    float* gi   = span + 786432;            // 2359296
    float* ctx  = gi + 2359296;             // 12288
    float* qv   = ctx + 12288;              // 1024
    float* kv   = qv + 1024;                // 1040
    int*   idxw = (int*)(kv + 1040);        // 8192
    // hpair ALIASES the span region (span is dead after gi_gemm; its
    // memset is enqueued after gi_gemm below). 24576 pairs * 8 B = 192 KiB.
    unsigned long long* hpair = (unsigned long long*)span;

    // output layout (floats)
    float* out      = (float*)d_out;
    float* o_repac  = out;                  // 786432
    float* o_repctx = out + 786432;         // 12288
    float* o_v1     = out + 798720;         // 6291456
    float* o_vals   = out + 7090176;        // 8192
    float* o_idx    = out + 7098368;        // 8192

    hipMemsetAsync(ctx, 0, (size_t)BB * DD * sizeof(float), stream);

    span_mean_kernel<<<1024, 256, 0, stream>>>(hidden, span_start, span_len, span);
    ctx_accum_kernel<<<dim3(BB, 32), 256, 0, stream>>>(hidden, attn_len, ctx);
    repctx_kernel<<<dim3(BB, 3), 256, 0, stream>>>(ctx, attn_len, W_ctx, b_ctx, o_repctx);
    gi_gemm_kernel<<<dim3(16, 18, 2), 256, 0, stream>>>(span, W_ih_f, W_ih_b,
                                                        b_ih_f, b_hh_f, b_ih_b, b_hh_b, gi);
    // span is now dead -> zero the aliased hpair region (h_0 = 0, tag = 0)
    hipMemsetAsync(hpair, 0, (size_t)24576 * sizeof(unsigned long long), stream);
    scan_coop_kernel<<<48, 256, 0, stream>>>(gi, W_hh_f, W_hh_b, b_hh_f, b_hh_b,
                                             hpair, o_repac);
    qkv_kernel<<<516, 256, 0, stream>>>(o_repac, o_repctx, W_find, qv, kv);
    topk_kernel<<<4, 256, 0, stream>>>(qv, kv, o_vals, o_idx, idxw);
    v1_kernel<<<1024, 256, 0, stream>>>(o_repac, o_repctx, idxw, o_v1);
}

// Round 5
// 905.112 us; speedup vs baseline: 1.5387x; 1.5387x over previous
//
#include <hip/hip_runtime.h>
#include <hip/hip_bf16.h>
#include <math.h>

#define BB 16
#define LL 4095
#define DD 768
#define TT 768
#define SS 64
#define KK 8
#define HH 384
#define G3 1152   // 3*H
#define NWPD 24   // WGs per direction for the coop scan

// ---------- 1. span means (float4-vectorized) ----------
__global__ void span_mean_kernel(const float* __restrict__ hidden,
                                 const int* __restrict__ sstart,
                                 const int* __restrict__ slen,
                                 float* __restrict__ span) {
    int bs = blockIdx.x;            // b*64+s
    int b = bs >> 6;
    int st = sstart[bs];
    int ln = slen[bs];
    const float4* base = (const float4*)(hidden + ((size_t)b * LL + st) * DD);
    float4* dst = (float4*)(span + (size_t)bs * DD);
    float inv = 1.0f / (float)ln;
    for (int d = threadIdx.x; d < DD / 4; d += 256) {
        float4 acc = make_float4(0.f, 0.f, 0.f, 0.f);
        for (int r = 0; r < ln; ++r) {
            float4 v = base[(size_t)r * (DD / 4) + d];
            acc.x += v.x; acc.y += v.y; acc.z += v.z; acc.w += v.w;
        }
        dst[d] = make_float4(acc.x * inv, acc.y * inv, acc.z * inv, acc.w * inv);
    }
}

// ---------- 2. ctx accumulation (atomic partial sums) ----------
__global__ void ctx_accum_kernel(const float* __restrict__ hidden,
                                 const int* __restrict__ attn_len,
                                 float* __restrict__ ctx) {
    int b = blockIdx.x, chunk = blockIdx.y;
    int lim = attn_len[b] - 1;
    int l0 = chunk * 128;
    int l1 = min(l0 + 128, lim);
    if (l0 >= l1) return;
    int t = threadIdx.x;
    const float* base = hidden + (size_t)b * LL * DD;
    float a0 = 0.f, a1 = 0.f, a2 = 0.f;
    for (int l = l0; l < l1; ++l) {
        const float* row = base + (size_t)l * DD;
        a0 += row[t]; a1 += row[t + 256]; a2 += row[t + 512];
    }
    atomicAdd(&ctx[b * DD + t], a0);
    atomicAdd(&ctx[b * DD + t + 256], a1);
    atomicAdd(&ctx[b * DD + t + 512], a2);
}

// ---------- 3. rep_context = (ctx/n) @ W_ctx^T + b_ctx ----------
__global__ void repctx_kernel(const float* __restrict__ ctxsum,
                              const int* __restrict__ attn_len,
                              const float* __restrict__ W_ctx,
                              const float* __restrict__ b_ctx,
                              float* __restrict__ out_rc) {
    int b = blockIdx.x;
    int j = blockIdx.y * 256 + threadIdx.x;
    __shared__ float cv[DD];
    float inv = 1.0f / (float)(attn_len[b] - 1);
    for (int d = threadIdx.x; d < DD; d += 256) cv[d] = ctxsum[b * DD + d] * inv;
    __syncthreads();
    const float* wr = W_ctx + (size_t)j * DD;
    float acc = b_ctx[j];
    for (int d = 0; d < DD; ++d) acc += wr[d] * cv[d];
    out_rc[b * TT + j] = acc;
}

// ---------- 4. gi = span @ W_ih^T + b_ih (+ b_hh for r,z gates) ----------
// LDS tiles stored TRANSPOSED [k][m] so the inner loop is 2x ds_read_b128
// + 16 FMA per kk instead of 8x ds_read_b32.
__global__ __launch_bounds__(256) void gi_gemm_kernel(
        const float* __restrict__ span,
        const float* __restrict__ Wf, const float* __restrict__ Wb,
        const float* __restrict__ bihf, const float* __restrict__ bhhf,
        const float* __restrict__ bihb, const float* __restrict__ bhhb,
        float* __restrict__ gi) {
    int dir = blockIdx.z;
    const float* W = dir ? Wb : Wf;
    const float* bih = dir ? bihb : bihf;
    const float* bhh = dir ? bhhb : bhhf;
    int m0 = blockIdx.x * 64, n0 = blockIdx.y * 64;
    __shared__ float As[16][68];   // [k][m], pad 68 (2-way max on stage writes)
    __shared__ float Bs[16][68];
    int t = threadIdx.x, tx = t & 15, ty = t >> 4;
    float acc[4][4] = {{0.f}};
    for (int k0 = 0; k0 < DD; k0 += 16) {
        for (int e = t; e < 1024; e += 256) {
            int r = e >> 4, c = e & 15;
            As[c][r] = span[(size_t)(m0 + r) * DD + k0 + c];
            Bs[c][r] = W[(size_t)(n0 + r) * DD + k0 + c];
        }
        __syncthreads();
#pragma unroll
        for (int kk = 0; kk < 16; ++kk) {
            float4 a4 = *(const float4*)&As[kk][ty * 4];
            float4 b4 = *(const float4*)&Bs[kk][tx * 4];
            float a[4] = {a4.x, a4.y, a4.z, a4.w};
            float bv[4] = {b4.x, b4.y, b4.z, b4.w};
#pragma unroll
            for (int i = 0; i < 4; ++i)
#pragma unroll
                for (int j = 0; j < 4; ++j) acc[i][j] += a[i] * bv[j];
        }
        __syncthreads();
    }
#pragma unroll
    for (int i = 0; i < 4; ++i)
#pragma unroll
        for (int j = 0; j < 4; ++j) {
            int m = m0 + ty * 4 + i, n = n0 + tx * 4 + j;
            float v = acc[i][j] + bih[n] + (n < 2 * HH ? bhh[n] : 0.0f);
            gi[((size_t)dir * 1024 + m) * G3 + n] = v;
        }
}

// ---------- 5. GRU coop scan (R3-exact, known-good 417 us) ----------
// Single-round-trip step protocol: each h element is published as an
// 8-byte atomic {tag = step, value} pair (one global_store_dwordx2 at
// agent scope, un-torn). Consumers poll-load the pairs directly: when
// the tag matches the expected step, the payload of the SAME load is
// the data. Relaxed-only atomics: ordering comes from the data
// dependency inside the single 8-byte pair.
__global__ __launch_bounds__(256, 1) void scan_coop_kernel(
        const float* __restrict__ gi,
        const float* __restrict__ Whf, const float* __restrict__ Whb,
        const float* __restrict__ bhhf, const float* __restrict__ bhhb,
        unsigned long long* __restrict__ hpair,  // [2 parity][2 dir][16 b][384]
        float* __restrict__ repac) {
    int wg = blockIdx.x;            // 0..47
    int dir = wg / NWPD;
    int w = wg % NWPD;
    int t = threadIdx.x;
    int kseg = t & 15, i_loc = t >> 4;
    int i_glob = w * 16 + i_loc;
    const float* Wh = dir ? Whb : Whf;

    // W fragments into registers (once):
    // thread (i_loc,kseg) holds W[g][i_glob][k] for k in {kseg*4 + 64j + q}
    float4 wr[3][6];
#pragma unroll
    for (int g = 0; g < 3; ++g)
#pragma unroll
        for (int j = 0; j < 6; ++j) {
            wr[g][j] = *(const float4*)(Wh + (size_t)(g * HH + i_glob) * HH + kseg * 4 + 64 * j);
            // opaque per-scalar touch: keeps the tile resident in VGPRs
            asm volatile("" : "+v"(wr[g][j].x), "+v"(wr[g][j].y),
                              "+v"(wr[g][j].z), "+v"(wr[g][j].w));
        }
    float bhn = (dir ? bhhb : bhhf)[2 * HH + i_glob];

    __shared__ __align__(16) float hs[6144];          // [16 b][384]
    float4* hs4 = (float4*)hs;

    for (int s = 0; s < 64; ++s) {
        int p = dir ? (63 - s) : s;
        // ---- gi loads for this thread's output (b = kseg, i_glob);
        //      independent of the poll, scheduled early ----
        const float* grow = gi + ((size_t)dir * 1024 + kseg * 64 + p) * G3;
        float g_r = grow[i_glob], g_z = grow[HH + i_glob], g_n = grow[2 * HH + i_glob];
        // ---- poll tagged h pairs: the poll IS the data load ----
        {
            const unsigned long long* src = hpair + (size_t)((s & 1) * 2 + dir) * 6144;
            unsigned int expect = (unsigned int)s;
            unsigned long long vals[24];
            for (;;) {
                bool ok = true;
#pragma unroll
                for (int j = 0; j < 24; ++j) {
                    vals[j] = __hip_atomic_load(src + j * 256 + t,
                                                __ATOMIC_RELAXED, __HIP_MEMORY_SCOPE_AGENT);
                    ok &= ((unsigned int)(vals[j] >> 32) == expect);
                }
                if (ok) break;
                __builtin_amdgcn_s_sleep(1);
            }
#pragma unroll
            for (int j = 0; j < 24; ++j)
                hs[j * 256 + t] = __uint_as_float((unsigned int)vals[j]);
        }
        __syncthreads();
        // ---- partials for all 16 batches over this thread's k-set ----
        float pr[16], pz[16], pn[16];
#pragma unroll
        for (int b = 0; b < 16; ++b) {
            float4 hq[6];
#pragma unroll
            for (int j = 0; j < 6; ++j) hq[j] = hs4[b * 96 + kseg + 16 * j];
            float ar = 0.f, az = 0.f, an = 0.f;
#pragma unroll
            for (int j = 0; j < 6; ++j) {
                ar += wr[0][j].x * hq[j].x + wr[0][j].y * hq[j].y + wr[0][j].z * hq[j].z + wr[0][j].w * hq[j].w;
                az += wr[1][j].x * hq[j].x + wr[1][j].y * hq[j].y + wr[1][j].z * hq[j].z + wr[1][j].w * hq[j].w;
                an += wr[2][j].x * hq[j].x + wr[2][j].y * hq[j].y + wr[2][j].z * hq[j].z + wr[2][j].w * hq[j].w;
            }
            pr[b] = ar; pz[b] = az; pn[b] = an;
        }
        // ---- butterfly reduce across the 16 kseg lanes; end: b == kseg ----
        float qr[8], qz[8], qn[8];
        {
            const bool hi = (kseg & 8) != 0;
#pragma unroll
            for (int j = 0; j < 8; ++j) {
                float sr_ = hi ? pr[j] : pr[j + 8];
                qr[j] = (hi ? pr[j + 8] : pr[j]) + __shfl_xor(sr_, 8);
                float sz_ = hi ? pz[j] : pz[j + 8];
                qz[j] = (hi ? pz[j + 8] : pz[j]) + __shfl_xor(sz_, 8);
                float sn_ = hi ? pn[j] : pn[j + 8];
                qn[j] = (hi ? pn[j + 8] : pn[j]) + __shfl_xor(sn_, 8);
            }
        }
        float ur[4], uz[4], un[4];
        {
            const bool hi = (kseg & 4) != 0;
#pragma unroll
            for (int j = 0; j < 4; ++j) {
                float sr_ = hi ? qr[j] : qr[j + 4];
                ur[j] = (hi ? qr[j + 4] : qr[j]) + __shfl_xor(sr_, 4);
                float sz_ = hi ? qz[j] : qz[j + 4];
                uz[j] = (hi ? qz[j + 4] : qz[j]) + __shfl_xor(sz_, 4);
                float sn_ = hi ? qn[j] : qn[j + 4];
                un[j] = (hi ? qn[j + 4] : qn[j]) + __shfl_xor(sn_, 4);
            }
        }
        float vr[2], vz[2], vn[2];
        {
            const bool hi = (kseg & 2) != 0;
#pragma unroll
            for (int j = 0; j < 2; ++j) {
                float sr_ = hi ? ur[j] : ur[j + 2];
                vr[j] = (hi ? ur[j + 2] : ur[j]) + __shfl_xor(sr_, 2);
                float sz_ = hi ? uz[j] : uz[j + 2];
                vz[j] = (hi ? uz[j + 2] : uz[j]) + __shfl_xor(sz_, 2);
                float sn_ = hi ? un[j] : un[j + 2];
                vn[j] = (hi ? un[j + 2] : un[j]) + __shfl_xor(sn_, 2);
            }
        }
        float sr, sz, sn;
        {
            const bool hi = (kseg & 1) != 0;
            float sr_ = hi ? vr[0] : vr[1];
            sr = (hi ? vr[1] : vr[0]) + __shfl_xor(sr_, 1);
            float sz_ = hi ? vz[0] : vz[1];
            sz = (hi ? vz[1] : vz[0]) + __shfl_xor(sz_, 1);
            float sn_ = hi ? vn[0] : vn[1];
            sn = (hi ? vn[1] : vn[0]) + __shfl_xor(sn_, 1);
        }
        // ---- epilogue: every thread owns one (b = kseg, i_glob) output ----
        float r = 1.0f / (1.0f + expf(-(g_r + sr)));
        float z = 1.0f / (1.0f + expf(-(g_z + sz)));
        float n = tanhf(g_n + r * (sn + bhn));
        float hold = hs[kseg * 384 + i_glob];
        float hnew = (1.0f - z) * n + z * hold;
        // publish {tag = s+1, h} as one 8-byte relaxed agent store
        unsigned long long pv = ((unsigned long long)(unsigned int)(s + 1) << 32)
                              | (unsigned long long)__float_as_uint(hnew);
        __hip_atomic_store(hpair + (size_t)(((s + 1) & 1) * 2 + dir) * 6144 + kseg * 384 + i_glob,
                           pv, __ATOMIC_RELAXED, __HIP_MEMORY_SCOPE_AGENT);
        repac[(size_t)(kseg * 64 + p) * TT + dir * HH + i_glob] = hnew;
        __syncthreads();   // protect hs (hold reads) before next step's LDS writes
    }
}

// ---------- 6. q and k dot products (one wave each, fp64 accumulation) ----------
__global__ void qkv_kernel(const float* __restrict__ repac,
                           const float* __restrict__ repctx,
                           const float* __restrict__ Wfind,
                           float* __restrict__ qv, float* __restrict__ kv) {
    int w = blockIdx.x * 4 + (threadIdx.x >> 6);
    int lane = threadIdx.x & 63;
    const float* row;
    const float* vec;
    float* dst;
    if (w < 1024) {
        row = repac + (size_t)w * TT;
        vec = Wfind;
        dst = qv + w;
    } else {
        int u = w - 1024;
        int b = u / 65, j = u % 65;
        row = (j < 64) ? (repac + (size_t)(b * 64 + j) * TT) : (repctx + (size_t)b * TT);
        vec = Wfind + TT;
        dst = kv + u;
    }
    double acc = 0.0;
    for (int d = lane; d < TT; d += 64) acc += (double)row[d] * (double)vec[d];
#pragma unroll
    for (int off = 32; off > 0; off >>= 1) acc += __shfl_down(acc, off);
    if (lane == 0) *dst = (float)acc;
}

// ---------- 7. top-k: fully-unrolled (sc[] in REGISTERS, not scratch),
// 16 blocks x 64 threads (one batch per block). Numerics identical. ----------
__global__ __launch_bounds__(64) void topk_kernel(
                            const float* __restrict__ qv,
                            const float* __restrict__ kv,
                            float* __restrict__ vals_out,
                            float* __restrict__ idx_out,
                            int* __restrict__ idxw) {
    int t = threadIdx.x;            // 0..63
    int b = blockIdx.x;             // batch
    int bs = b * 64 + t;
    __shared__ float kvs[65];
    for (int e = t; e < 65; e += 64) kvs[e] = kv[b * 65 + e];
    __syncthreads();
    float q = qv[bs];
    float sc[65];
#pragma unroll
    for (int j = 0; j < 65; ++j) {
        float x = q + kvs[j];                 // fp32 add, as np broadcast-add
        float e = (float)exp(-(double)x);     // ~correctly-rounded f32 exp
        sc[j] = 1.0f / (1.0f + e);            // fp32 add + fp32 divide, as np
    }
    unsigned long long taken = 0ull;
    bool tk64 = false;
    for (int kk = 0; kk < 8; ++kk) {
        float best = -3.0e38f;
        int bj = 0;
#pragma unroll
        for (int j = 0; j < 65; ++j) {
            bool tkn = (j < 64) ? (((taken >> j) & 1ull) != 0ull) : tk64;
            float v = sc[j];
            if (!tkn && v > best) { best = v; bj = j; }   // strict > => lowest index wins ties
        }
        if (bj < 64) taken |= (1ull << bj); else tk64 = true;
        vals_out[bs * 8 + kk] = best;
        idx_out[bs * 8 + kk] = (float)bj;
        idxw[bs * 8 + kk] = bj;
    }
}

// ---------- 8. v1 gather (float4) ----------
__global__ void v1_kernel(const float* __restrict__ repac,
                          const float* __restrict__ repctx,
                          const int* __restrict__ idxw,
                          float* __restrict__ v1) {
    int bs = blockIdx.x;
    int b = bs >> 6;
    int t = threadIdx.x;
    for (int kk = 0; kk < 8; ++kk) {
        int j = idxw[bs * 8 + kk];
        const float4* src = (const float4*)((j < 64) ? (repac + (size_t)(b * 64 + j) * TT)
                                                     : (repctx + (size_t)b * TT));
        float4* dst = (float4*)(v1 + ((size_t)bs * 8 + kk) * TT);
        for (int d = t; d < DD / 4; d += 256) dst[d] = src[d];
    }
}

extern "C" void kernel_launch(void* const* d_in, const int* in_sizes, int n_in,
                              void* d_out, int out_size, void* d_ws, size_t ws_size,
                              hipStream_t stream) {
    const float* hidden    = (const float*)d_in[0];
    const float* W_ih_f    = (const float*)d_in[1];
    const float* W_hh_f    = (const float*)d_in[2];
    const float* b_ih_f    = (const float*)d_in[3];
    const float* b_hh_f    = (const float*)d_in[4];
    const float* W_ih_b    = (const float*)d_in[5];
    const float* W_hh_b    = (const float*)d_in[6];
    const float* b_ih_b    = (const float*)d_in[7];
    const float* b_hh_b    = (const float*)d_in[8];
    const float* W_ctx     = (const float*)d_in[9];
    const float* b_ctx     = (const float*)d_in[10];
    const float* W_find    = (const float*)d_in[11];
    const int*   attn_len  = (const int*)d_in[12];
    const int*   span_start= (const int*)d_in[13];
    const int*   span_len  = (const int*)d_in[14];
    (void)in_sizes; (void)n_in; (void)out_size; (void)ws_size;

    // workspace layout (floats)
    float* ws   = (float*)d_ws;
    float* span = ws;                       // 786432
    float* gi   = span + 786432;            // 2359296
    float* ctx  = gi + 2359296;             // 12288
    float* qv   = ctx + 12288;              // 1024
    float* kv   = qv + 1024;                // 1040
    int*   idxw = (int*)(kv + 1040);        // 8192
    // hpair ALIASES the span region (span is dead after gi_gemm; its
    // memset is enqueued after gi_gemm below). 24576 pairs * 8 B = 192 KiB.
    unsigned long long* hpair = (unsigned long long*)span;

    // output layout (floats)
    float* out      = (float*)d_out;
    float* o_repac  = out;                  // 786432
    float* o_repctx = out + 786432;         // 12288
    float* o_v1     = out + 798720;         // 6291456
    float* o_vals   = out + 7090176;        // 8192
    float* o_idx    = out + 7098368;        // 8192

    hipMemsetAsync(ctx, 0, (size_t)BB * DD * sizeof(float), stream);

    span_mean_kernel<<<1024, 256, 0, stream>>>(hidden, span_start, span_len, span);
    ctx_accum_kernel<<<dim3(BB, 32), 256, 0, stream>>>(hidden, attn_len, ctx);
    repctx_kernel<<<dim3(BB, 3), 256, 0, stream>>>(ctx, attn_len, W_ctx, b_ctx, o_repctx);
    gi_gemm_kernel<<<dim3(16, 18, 2), 256, 0, stream>>>(span, W_ih_f, W_ih_b,
                                                        b_ih_f, b_hh_f, b_ih_b, b_hh_b, gi);
    // span is now dead -> zero the aliased hpair region (h_0 = 0, tag = 0)
    hipMemsetAsync(hpair, 0, (size_t)24576 * sizeof(unsigned long long), stream);
    scan_coop_kernel<<<48, 256, 0, stream>>>(gi, W_hh_f, W_hh_b, b_hh_f, b_hh_b,
                                             hpair, o_repac);
    qkv_kernel<<<516, 256, 0, stream>>>(o_repac, o_repctx, W_find, qv, kv);
    topk_kernel<<<16, 64, 0, stream>>>(qv, kv, o_vals, o_idx, idxw);
    v1_kernel<<<1024, 256, 0, stream>>>(o_repac, o_repctx, idxw, o_v1);
}